// Round 8
// baseline (1936.506 us; speedup 1.0000x reference)
//
#include <hip/hip_runtime.h>
#include <hip/hip_fp16.h>

#define ND 56
#define HD 64
#define S1 60   // W1T row stride (words): [h=64][d=56 pad 60]
#define S2 68   // W2T row stride (words): [h=64][k=64 pad 68]
#define DEDD_H2 32  // dEdD row = 32 half2 = 64 halfs = 128B (56 used)

typedef float v4f __attribute__((ext_vector_type(4)));
typedef _Float16 v4h __attribute__((ext_vector_type(4)));

__global__ __launch_bounds__(256) void zero_kernel(float* __restrict__ p, int n) {
    int i = blockIdx.x * 256 + threadIdx.x;
    if (i < n) p[i] = 0.f;
}

// Persistent MLP fwd+bwd (round-5 version). One wave = 4 atoms.
// REPS>1 instances are timing probes (identical code path, repeated).
template <int REPS>
__global__ __launch_bounds__(256) void mlp_kernel(
    const float* __restrict__ x,        // [natoms*ND]
    const int*   __restrict__ indices,  // [natoms]
    const float* __restrict__ W1,       // [ND*HD]
    const float* __restrict__ b1,       // [HD]
    const float* __restrict__ W2,       // [HD*HD]
    const float* __restrict__ b2,       // [HD]
    const float* __restrict__ W3,       // [HD]
    const float* __restrict__ b3,       // [1]
    float* __restrict__ out_e,          // [nconf]
    __half2* __restrict__ dEdD,         // [natoms*DEDD_H2]
    int natoms)
{
    __shared__ float W1T[HD * S1 + 4];
    __shared__ float W2T[HD * S2];
    __shared__ float b1s[HD], b2s[HD], W3s[HD];
    __shared__ float xs[16 * ND];
    __shared__ float hbuf[4][4][HD];
    __shared__ float gbuf[4][4][HD];

    const int tid = threadIdx.x;
    for (int i = tid; i < ND * HD; i += 256) W1T[(i % HD) * S1 + (i / HD)] = W1[i];
    for (int i = tid; i < HD * HD; i += 256) W2T[(i % HD) * S2 + (i / HD)] = W2[i];
    if (tid < HD) { b1s[tid] = b1[tid]; b2s[tid] = b2[tid]; W3s[tid] = W3[tid]; }
    __syncthreads();

    const int w = tid >> 6, lane = tid & 63;
    const float b3v = b3[0];
    const float b1v = b1s[lane], b2v = b2s[lane], w3v = W3s[lane];
    const int nGroups = (natoms + 15) >> 4;

    for (int rep = 0; rep < REPS; ++rep) {
    for (int grp = blockIdx.x; grp < nGroups; grp += gridDim.x) {
        const int abase = grp * 16 + w * 4;

        if (lane < 56) {
            const int a = lane / 14;
            if (abase + a < natoms)
                reinterpret_cast<float4*>(xs + w * 4 * ND)[lane] =
                    reinterpret_cast<const float4*>(x)[(size_t)abase * 14 + lane];
        }

        float4 acc[4];
        // ---- fwd layer 1 ----
        #pragma unroll
        for (int a = 0; a < 4; ++a) acc[a] = float4{0.f, 0.f, 0.f, 0.f};
        #pragma unroll
        for (int i = 0; i < 14; ++i) {
            const float4 wv = *reinterpret_cast<const float4*>(&W1T[lane * S1 + 4 * i]);
            #pragma unroll
            for (int a = 0; a < 4; ++a) {
                const float4 xv = *reinterpret_cast<const float4*>(&xs[(w * 4 + a) * ND + 4 * i]);
                acc[a].x = fmaf(wv.x, xv.x, acc[a].x);
                acc[a].y = fmaf(wv.y, xv.y, acc[a].y);
                acc[a].z = fmaf(wv.z, xv.z, acc[a].z);
                acc[a].w = fmaf(wv.w, xv.w, acc[a].w);
            }
        }
        float z1[4], s1[4];
        #pragma unroll
        for (int a = 0; a < 4; ++a) {
            z1[a] = b1v + ((acc[a].x + acc[a].y) + (acc[a].z + acc[a].w));
            s1[a] = 1.f / (1.f + __expf(-z1[a]));
            hbuf[w][a][lane] = z1[a] * s1[a];
        }

        // ---- fwd layer 2 + energy + g2 ----
        #pragma unroll
        for (int a = 0; a < 4; ++a) acc[a] = float4{0.f, 0.f, 0.f, 0.f};
        #pragma unroll
        for (int i = 0; i < 16; ++i) {
            const float4 wv = *reinterpret_cast<const float4*>(&W2T[lane * S2 + 4 * i]);
            #pragma unroll
            for (int a = 0; a < 4; ++a) {
                const float4 hv = *reinterpret_cast<const float4*>(&hbuf[w][a][4 * i]);
                acc[a].x = fmaf(wv.x, hv.x, acc[a].x);
                acc[a].y = fmaf(wv.y, hv.y, acc[a].y);
                acc[a].z = fmaf(wv.z, hv.z, acc[a].z);
                acc[a].w = fmaf(wv.w, hv.w, acc[a].w);
            }
        }
        float ev[4];
        #pragma unroll
        for (int a = 0; a < 4; ++a) {
            const float z2 = b2v + ((acc[a].x + acc[a].y) + (acc[a].z + acc[a].w));
            const float s2 = 1.f / (1.f + __expf(-z2));
            ev[a] = (z2 * s2) * w3v;
            gbuf[w][a][lane] = w3v * (s2 * (1.f + z2 * (1.f - s2)));
        }
        #pragma unroll
        for (int off = 32; off > 0; off >>= 1) {
            #pragma unroll
            for (int a = 0; a < 4; ++a) ev[a] += __shfl_xor(ev[a], off);
        }
        if (lane == 0) {
            #pragma unroll
            for (int a = 0; a < 4; ++a)
                if (abase + a < natoms)
                    unsafeAtomicAdd(&out_e[indices[abase + a]], ev[a] + b3v);
        }

        // ---- bwd: dh1 -> g1 ----
        #pragma unroll
        for (int a = 0; a < 4; ++a) acc[a] = float4{0.f, 0.f, 0.f, 0.f};
        #pragma unroll
        for (int i = 0; i < 16; ++i) {
            const float w0 = W2T[(4 * i + 0) * S2 + lane];
            const float w1v = W2T[(4 * i + 1) * S2 + lane];
            const float w2v = W2T[(4 * i + 2) * S2 + lane];
            const float w3x = W2T[(4 * i + 3) * S2 + lane];
            #pragma unroll
            for (int a = 0; a < 4; ++a) {
                const float4 gv = *reinterpret_cast<const float4*>(&gbuf[w][a][4 * i]);
                acc[a].x = fmaf(w0, gv.x, acc[a].x);
                acc[a].y = fmaf(w1v, gv.y, acc[a].y);
                acc[a].z = fmaf(w2v, gv.z, acc[a].z);
                acc[a].w = fmaf(w3x, gv.w, acc[a].w);
            }
        }
        #pragma unroll
        for (int a = 0; a < 4; ++a) {
            const float dh1 = (acc[a].x + acc[a].y) + (acc[a].z + acc[a].w);
            hbuf[w][a][lane] = dh1 * (s1[a] * (1.f + z1[a] * (1.f - s1[a])));
        }

        // ---- bwd: dx ----
        #pragma unroll
        for (int a = 0; a < 4; ++a) acc[a] = float4{0.f, 0.f, 0.f, 0.f};
        #pragma unroll
        for (int i = 0; i < 16; ++i) {
            const float w0 = W1T[(4 * i + 0) * S1 + lane];
            const float w1v = W1T[(4 * i + 1) * S1 + lane];
            const float w2v = W1T[(4 * i + 2) * S1 + lane];
            const float w3x = W1T[(4 * i + 3) * S1 + lane];
            #pragma unroll
            for (int a = 0; a < 4; ++a) {
                const float4 gv = *reinterpret_cast<const float4*>(&hbuf[w][a][4 * i]);
                acc[a].x = fmaf(w0, gv.x, acc[a].x);
                acc[a].y = fmaf(w1v, gv.y, acc[a].y);
                acc[a].z = fmaf(w2v, gv.z, acc[a].z);
                acc[a].w = fmaf(w3x, gv.w, acc[a].w);
            }
        }
        #pragma unroll
        for (int a = 0; a < 4; ++a) {
            const float v  = (acc[a].x + acc[a].y) + (acc[a].z + acc[a].w);
            const float vh = __shfl_down(v, 1);
            if ((lane & 1) == 0 && lane < ND && abase + a < natoms)
                dEdD[(size_t)(abase + a) * DEDD_H2 + (lane >> 1)] =
                    __floats2half2_rn(v, vh);
        }
    }
    }
}

// Fused force kernel (round-5 version). REPS>1 = probe.
template <int REPS>
__global__ __launch_bounds__(256) void force_kernel(
    const float* __restrict__ xd,       // [M*ND]
    const int*   __restrict__ xd_indx,  // [M*3]
    const int*   __restrict__ unique_j, // [M]
    const _Float16* __restrict__ dEdD,  // [natoms*64] halfs
    float* __restrict__ out_f,          // [3*natoms]
    int M)
{
    const long t = (long)blockIdx.x * 256 + threadIdx.x;
    const int  m   = (int)(t >> 4);
    const int  sub = (int)(t & 15);

    for (int rep = 0; rep < REPS; ++rep) {
        float partial = 0.f;
        if (m < M) {
            const int a = __builtin_nontemporal_load(xd_indx + 3 * (size_t)m);
            if (sub < 14) {
                const v4f u = __builtin_nontemporal_load(
                    reinterpret_cast<const v4f*>(xd) + (size_t)m * 14 + sub);
                const v4h hv = reinterpret_cast<const v4h*>(dEdD + ((size_t)a << 6))[sub];
                partial = fmaf(u.x, (float)hv.x,
                          fmaf(u.y, (float)hv.y,
                          fmaf(u.z, (float)hv.z, u.w * (float)hv.w)));
            }
        }
        partial += __shfl_xor(partial, 1);
        partial += __shfl_xor(partial, 2);
        partial += __shfl_xor(partial, 4);
        partial += __shfl_xor(partial, 8);

        if (m < M && sub == 0) {
            const int coord = __builtin_nontemporal_load(xd_indx + 3 * (size_t)m + 2);
            const int j     = __builtin_nontemporal_load(unique_j + m);
            unsafeAtomicAdd(&out_f[(size_t)j * 3 + coord], partial);
        }
    }
}

extern "C" void kernel_launch(void* const* d_in, const int* in_sizes, int n_in,
                              void* d_out, int out_size, void* d_ws, size_t ws_size,
                              hipStream_t stream) {
    const float* x        = (const float*)d_in[0];
    const float* xd       = (const float*)d_in[1];
    const int*   indices  = (const int*)d_in[2];
    const int*   xd_indx  = (const int*)d_in[4];
    const int*   unique_j = (const int*)d_in[5];
    const float* W1 = (const float*)d_in[6];
    const float* b1 = (const float*)d_in[7];
    const float* W2 = (const float*)d_in[8];
    const float* b2 = (const float*)d_in[9];
    const float* W3 = (const float*)d_in[10];
    const float* b3 = (const float*)d_in[11];

    const int natoms = in_sizes[0] / ND;
    const int M      = in_sizes[1] / ND;
    const int nconf  = in_sizes[3];

    float*    out_e  = (float*)d_out;          // [nconf]
    float*    out_f  = out_e + nconf;          // [3*natoms]
    __half2*  dEdD2  = (__half2*)d_ws;         // [natoms*32] half2 (6.4 MB)
    _Float16* dEdDh  = (_Float16*)d_ws;

    // probe scratch, far from live data (ws ~2.7 GB per harness fill size)
    float*    dum_e  = (float*)((char*)d_ws + (256u << 20));
    float*    dum_f  = dum_e + nconf;
    __half2*  dum_d2 = (__half2*)((char*)d_ws + (320u << 20));

    const int nGroups = (natoms + 15) >> 4;
    const int mlpGrid = nGroups < 768 ? nGroups : 768;
    const long fthreads = (long)M * 16;
    const unsigned fGrid = (unsigned)((fthreads + 255) / 256);

    // ---- real sequence (identical to round 5) ----
    zero_kernel<<<(out_size + 255) / 256, 256, 0, stream>>>((float*)d_out, out_size);

    mlp_kernel<1><<<mlpGrid, 256, 0, stream>>>(
        x, indices, W1, b1, W2, b2, W3, b3, out_e, dEdD2, natoms);

    force_kernel<1><<<fGrid, 256, 0, stream>>>(
        xd, xd_indx, unique_j, dEdDh, out_f, M);

    // ---- diagnostic probes (outputs -> far scratch; long enough to rank
    //      above the harness fills in rocprof top-5 and expose counters) ----
    mlp_kernel<3><<<mlpGrid, 256, 0, stream>>>(
        x, indices, W1, b1, W2, b2, W3, b3, dum_e, dum_d2, natoms);

    force_kernel<4><<<fGrid, 256, 0, stream>>>(
        xd, xd_indx, unique_j, dEdDh, dum_f, M);
}

// Round 9
// 345.855 us; speedup vs baseline: 5.5992x; 5.5992x over previous
//
#include <hip/hip_runtime.h>
#include <hip/hip_fp16.h>

#define ND 56
#define HD 64
#define S1 60   // W1T row stride (words)
#define S2 68   // W2T row stride (words)
#define DEDD_H2 32  // dEdD row = 32 half2 = 64 halfs = 128B (56 used)
#define NREP 4      // force accumulator replicas
#define ESUM_MAX 1024

typedef float v4f __attribute__((ext_vector_type(4)));
typedef _Float16 v4h __attribute__((ext_vector_type(4)));

__global__ __launch_bounds__(256) void zero_kernel(float* __restrict__ p, int n) {
    int i = blockIdx.x * 256 + threadIdx.x;
    if (i < n) p[i] = 0.f;
}

// Persistent MLP fwd+bwd. One wave = 4 atoms (lane = hidden unit).
// Energy: LDS per-config accumulation (ds_add_f32), ONE global atomic per
// (block, touched config) at kernel end -> kills the 50K same-address
// write-through atomics that cost ~200us.
__global__ __launch_bounds__(256) void mlp_kernel(
    const float* __restrict__ x,        // [natoms*ND]
    const int*   __restrict__ indices,  // [natoms]
    const float* __restrict__ W1,       // [ND*HD]
    const float* __restrict__ b1,       // [HD]
    const float* __restrict__ W2,       // [HD*HD]
    const float* __restrict__ b2,       // [HD]
    const float* __restrict__ W3,       // [HD]
    const float* __restrict__ b3,       // [1]
    float* __restrict__ e_acc,          // [nconf] (ws, pre-zeroed)
    __half2* __restrict__ dEdD,         // [natoms*DEDD_H2]
    int natoms, int nconf)
{
    __shared__ float W1T[HD * S1 + 4];
    __shared__ float W2T[HD * S2];
    __shared__ float b1s[HD], b2s[HD], W3s[HD];
    __shared__ float xs[16 * ND];
    __shared__ float hbuf[4][4][HD];
    __shared__ float gbuf[4][4][HD];
    __shared__ float esum[ESUM_MAX];

    const int tid = threadIdx.x;
    for (int i = tid; i < ND * HD; i += 256) W1T[(i % HD) * S1 + (i / HD)] = W1[i];
    for (int i = tid; i < HD * HD; i += 256) W2T[(i % HD) * S2 + (i / HD)] = W2[i];
    for (int i = tid; i < ESUM_MAX; i += 256) esum[i] = 0.f;
    if (tid < HD) { b1s[tid] = b1[tid]; b2s[tid] = b2[tid]; W3s[tid] = W3[tid]; }
    __syncthreads();

    const int w = tid >> 6, lane = tid & 63;
    const float b3v = b3[0];
    const float b1v = b1s[lane], b2v = b2s[lane], w3v = W3s[lane];
    const int nGroups = (natoms + 15) >> 4;
    const bool ldsE = (nconf <= ESUM_MAX);

    for (int grp = blockIdx.x; grp < nGroups; grp += gridDim.x) {
        const int abase = grp * 16 + w * 4;

        if (lane < 56) {
            const int a = lane / 14;
            if (abase + a < natoms)
                reinterpret_cast<float4*>(xs + w * 4 * ND)[lane] =
                    reinterpret_cast<const float4*>(x)[(size_t)abase * 14 + lane];
        }

        float4 acc[4];
        // ---- fwd layer 1 ----
        #pragma unroll
        for (int a = 0; a < 4; ++a) acc[a] = float4{0.f, 0.f, 0.f, 0.f};
        #pragma unroll
        for (int i = 0; i < 14; ++i) {
            const float4 wv = *reinterpret_cast<const float4*>(&W1T[lane * S1 + 4 * i]);
            #pragma unroll
            for (int a = 0; a < 4; ++a) {
                const float4 xv = *reinterpret_cast<const float4*>(&xs[(w * 4 + a) * ND + 4 * i]);
                acc[a].x = fmaf(wv.x, xv.x, acc[a].x);
                acc[a].y = fmaf(wv.y, xv.y, acc[a].y);
                acc[a].z = fmaf(wv.z, xv.z, acc[a].z);
                acc[a].w = fmaf(wv.w, xv.w, acc[a].w);
            }
        }
        float z1[4], s1[4];
        #pragma unroll
        for (int a = 0; a < 4; ++a) {
            z1[a] = b1v + ((acc[a].x + acc[a].y) + (acc[a].z + acc[a].w));
            s1[a] = 1.f / (1.f + __expf(-z1[a]));
            hbuf[w][a][lane] = z1[a] * s1[a];
        }

        // ---- fwd layer 2 + energy + g2 ----
        #pragma unroll
        for (int a = 0; a < 4; ++a) acc[a] = float4{0.f, 0.f, 0.f, 0.f};
        #pragma unroll
        for (int i = 0; i < 16; ++i) {
            const float4 wv = *reinterpret_cast<const float4*>(&W2T[lane * S2 + 4 * i]);
            #pragma unroll
            for (int a = 0; a < 4; ++a) {
                const float4 hv = *reinterpret_cast<const float4*>(&hbuf[w][a][4 * i]);
                acc[a].x = fmaf(wv.x, hv.x, acc[a].x);
                acc[a].y = fmaf(wv.y, hv.y, acc[a].y);
                acc[a].z = fmaf(wv.z, hv.z, acc[a].z);
                acc[a].w = fmaf(wv.w, hv.w, acc[a].w);
            }
        }
        float ev[4];
        #pragma unroll
        for (int a = 0; a < 4; ++a) {
            const float z2 = b2v + ((acc[a].x + acc[a].y) + (acc[a].z + acc[a].w));
            const float s2 = 1.f / (1.f + __expf(-z2));
            ev[a] = (z2 * s2) * w3v;
            gbuf[w][a][lane] = w3v * (s2 * (1.f + z2 * (1.f - s2)));
        }
        #pragma unroll
        for (int off = 32; off > 0; off >>= 1) {
            #pragma unroll
            for (int a = 0; a < 4; ++a) ev[a] += __shfl_xor(ev[a], off);
        }
        if (lane == 0) {
            #pragma unroll
            for (int a = 0; a < 4; ++a)
                if (abase + a < natoms) {
                    const int conf = indices[abase + a];
                    if (ldsE) atomicAdd(&esum[conf], ev[a] + b3v);
                    else      unsafeAtomicAdd(&e_acc[conf], ev[a] + b3v);
                }
        }

        // ---- bwd: dh1 -> g1 ----
        #pragma unroll
        for (int a = 0; a < 4; ++a) acc[a] = float4{0.f, 0.f, 0.f, 0.f};
        #pragma unroll
        for (int i = 0; i < 16; ++i) {
            const float w0 = W2T[(4 * i + 0) * S2 + lane];
            const float w1v = W2T[(4 * i + 1) * S2 + lane];
            const float w2v = W2T[(4 * i + 2) * S2 + lane];
            const float w3x = W2T[(4 * i + 3) * S2 + lane];
            #pragma unroll
            for (int a = 0; a < 4; ++a) {
                const float4 gv = *reinterpret_cast<const float4*>(&gbuf[w][a][4 * i]);
                acc[a].x = fmaf(w0, gv.x, acc[a].x);
                acc[a].y = fmaf(w1v, gv.y, acc[a].y);
                acc[a].z = fmaf(w2v, gv.z, acc[a].z);
                acc[a].w = fmaf(w3x, gv.w, acc[a].w);
            }
        }
        #pragma unroll
        for (int a = 0; a < 4; ++a) {
            const float dh1 = (acc[a].x + acc[a].y) + (acc[a].z + acc[a].w);
            hbuf[w][a][lane] = dh1 * (s1[a] * (1.f + z1[a] * (1.f - s1[a])));
        }

        // ---- bwd: dx ----
        #pragma unroll
        for (int a = 0; a < 4; ++a) acc[a] = float4{0.f, 0.f, 0.f, 0.f};
        #pragma unroll
        for (int i = 0; i < 16; ++i) {
            const float w0 = W1T[(4 * i + 0) * S1 + lane];
            const float w1v = W1T[(4 * i + 1) * S1 + lane];
            const float w2v = W1T[(4 * i + 2) * S1 + lane];
            const float w3x = W1T[(4 * i + 3) * S1 + lane];
            #pragma unroll
            for (int a = 0; a < 4; ++a) {
                const float4 gv = *reinterpret_cast<const float4*>(&hbuf[w][a][4 * i]);
                acc[a].x = fmaf(w0, gv.x, acc[a].x);
                acc[a].y = fmaf(w1v, gv.y, acc[a].y);
                acc[a].z = fmaf(w2v, gv.z, acc[a].z);
                acc[a].w = fmaf(w3x, gv.w, acc[a].w);
            }
        }
        #pragma unroll
        for (int a = 0; a < 4; ++a) {
            const float v  = (acc[a].x + acc[a].y) + (acc[a].z + acc[a].w);
            const float vh = __shfl_down(v, 1);
            if ((lane & 1) == 0 && lane < ND && abase + a < natoms)
                dEdD[(size_t)(abase + a) * DEDD_H2 + (lane >> 1)] =
                    __floats2half2_rn(v, vh);
        }
    }

    // flush per-block energy partials: ~4-5 touched configs per block
    if (ldsE) {
        __syncthreads();
        for (int c = tid; c < nconf; c += 256) {
            const float v = esum[c];
            if (v != 0.f) unsafeAtomicAdd(&e_acc[c], v);
        }
    }
}

// Fused force kernel: 16 lanes per row; scatter into one of NREP replica
// accumulators (blockIdx-keyed) to cut same-address serialization 4x.
__global__ __launch_bounds__(256) void force_kernel(
    const float* __restrict__ xd,       // [M*ND]
    const int*   __restrict__ xd_indx,  // [M*3]
    const int*   __restrict__ unique_j, // [M]
    const _Float16* __restrict__ dEdD,  // [natoms*64] halfs
    float* __restrict__ f_rep,          // [NREP * 3*natoms] (ws, pre-zeroed)
    int M, int n3)
{
    const long t = (long)blockIdx.x * 256 + threadIdx.x;
    const int  m   = (int)(t >> 4);
    const int  sub = (int)(t & 15);

    float partial = 0.f;
    if (m < M) {
        const int a = __builtin_nontemporal_load(xd_indx + 3 * (size_t)m);
        if (sub < 14) {
            const v4f u = __builtin_nontemporal_load(
                reinterpret_cast<const v4f*>(xd) + (size_t)m * 14 + sub);
            const v4h hv = reinterpret_cast<const v4h*>(dEdD + ((size_t)a << 6))[sub];
            partial = fmaf(u.x, (float)hv.x,
                      fmaf(u.y, (float)hv.y,
                      fmaf(u.z, (float)hv.z, u.w * (float)hv.w)));
        }
    }
    partial += __shfl_xor(partial, 1);
    partial += __shfl_xor(partial, 2);
    partial += __shfl_xor(partial, 4);
    partial += __shfl_xor(partial, 8);

    if (m < M && sub == 0) {
        const int coord = __builtin_nontemporal_load(xd_indx + 3 * (size_t)m + 2);
        const int j     = __builtin_nontemporal_load(unique_j + m);
        float* dst = f_rep + (size_t)(blockIdx.x & (NREP - 1)) * n3;
        unsafeAtomicAdd(&dst[(size_t)j * 3 + coord], partial);
    }
}

// Merge: out[0:nconf] = e_acc; out[nconf + i] = sum_k f_rep[k][i].
// Writes every output element -> no d_out pre-zero needed.
__global__ __launch_bounds__(256) void merge_kernel(
    const float* __restrict__ e_acc, const float* __restrict__ f_rep,
    float* __restrict__ out, int nconf, int n3)
{
    const int i = blockIdx.x * 256 + threadIdx.x;
    if (i < nconf) {
        out[i] = e_acc[i];
    } else if (i < nconf + n3) {
        const int j = i - nconf;
        float s = 0.f;
        #pragma unroll
        for (int k = 0; k < NREP; ++k) s += f_rep[(size_t)k * n3 + j];
        out[i] = s;
    }
}

extern "C" void kernel_launch(void* const* d_in, const int* in_sizes, int n_in,
                              void* d_out, int out_size, void* d_ws, size_t ws_size,
                              hipStream_t stream) {
    const float* x        = (const float*)d_in[0];
    const float* xd       = (const float*)d_in[1];
    const int*   indices  = (const int*)d_in[2];
    const int*   xd_indx  = (const int*)d_in[4];
    const int*   unique_j = (const int*)d_in[5];
    const float* W1 = (const float*)d_in[6];
    const float* b1 = (const float*)d_in[7];
    const float* W2 = (const float*)d_in[8];
    const float* b2 = (const float*)d_in[9];
    const float* W3 = (const float*)d_in[10];
    const float* b3 = (const float*)d_in[11];

    const int natoms = in_sizes[0] / ND;
    const int M      = in_sizes[1] / ND;
    const int nconf  = in_sizes[3];
    const int n3     = 3 * natoms;

    __half2*  dEdD2 = (__half2*)d_ws;                       // [natoms*32] (6.4 MB)
    _Float16* dEdDh = (_Float16*)d_ws;
    // accumulators: e_acc then f_rep, contiguous for a single zero pass
    float* e_acc = (float*)((char*)d_ws + (64u << 20));     // [nconf] (pad to 512)
    float* f_rep = e_acc + 512;                             // [NREP*n3] (2.4 MB)
    const int accN = 512 + NREP * n3;

    zero_kernel<<<(accN + 255) / 256, 256, 0, stream>>>(e_acc, accN);

    const int nGroups = (natoms + 15) >> 4;
    const int mlpGrid = nGroups < 768 ? nGroups : 768;
    mlp_kernel<<<mlpGrid, 256, 0, stream>>>(
        x, indices, W1, b1, W2, b2, W3, b3, e_acc, dEdD2, natoms, nconf);

    const long fthreads = (long)M * 16;
    force_kernel<<<(unsigned)((fthreads + 255) / 256), 256, 0, stream>>>(
        xd, xd_indx, unique_j, dEdDh, f_rep, M, n3);

    merge_kernel<<<(nconf + n3 + 255) / 256, 256, 0, stream>>>(
        e_acc, f_rep, (float*)d_out, nconf, n3);
}